// Round 1
// baseline (175.427 us; speedup 1.0000x reference)
//
#include <hip/hip_runtime.h>

// FeatureRefine, MI355X/gfx950 — round 6.
// R5 counters: fr_refine 67us, VGPR=60, VALUBusy 31%, Occ 36%, hbm 51% peak,
// FETCH 201MB. Diagnosis: latency-bound gather loop — at 60 VGPRs the
// compiler serializes the 11 uint4 gather loads per point-set (each a
// ~500-600cy L2/L3 round trip; gathers are RANDOM over the 8MB batch plane,
// cx,cy ~ U(0,image)). Changes:
//  1. fr_refine v2: all 11 row loads issued into explicit uint4 arrays
//     BEFORE the fma chain; __launch_bounds__(256,4) caps VGPR at 128
//     (occupancy is LDS-capped at 4 blocks/CU = 16 waves regardless).
//     MLP 2 -> 11 outstanding 1KB loads/wave.
//  2. geo pass fused into the transpose kernel (t<256 computes geometry for
//     the block's own 256 pixels, overlapped with tile loads) — one fewer
//     dispatch.

#define N_ 4
#define C_ 256
#define H_ 128
#define W_ 128
#define HW_ (H_ * W_)
#define SCALE 0.125f

typedef unsigned int uint32;

__device__ __forceinline__ uint32 f2bf(float f) {
    uint32 u = __float_as_uint(f);
    u = (u + 0x7FFF + ((u >> 16) & 1)) >> 16;   // RNE
    return u;
}
__device__ __forceinline__ float blo(uint32 u) { return __uint_as_float(u << 16); }
__device__ __forceinline__ float bhi(uint32 u) { return __uint_as_float(u & 0xFFFF0000u); }

// ---------- Pass 0: NCHW fp32 -> NHWC bf16 (packed ch-pairs) + fused geo ----------
// 1024 thr / 16 waves; tile 256 hw x 256 c; LDS [cpair][hw] stride 260 (130 KB).
// Threads t<256 additionally compute the 128B geometry record for the block's
// 256 pixels (same (n, hw0..hw0+255) range) — overlaps with tile loads of the
// other 12 waves; saves the separate geo dispatch.
__global__ __launch_bounds__(1024) void nchw2nhwc_geo(const float* __restrict__ in,
                                                      const float* __restrict__ bb,
                                                      uint32* __restrict__ outU,
                                                      uint32* __restrict__ geoG)
{
    __shared__ uint32 tile[128 * 260];
    const int t   = threadIdx.x;
    const int l   = t & 63;
    const int g   = t >> 6;               // wave 0..15
    const int hw0 = blockIdx.x * 256;
    const int n   = blockIdx.y;

    if (t < 256) {                         // fused geo for this block's pixels
        const int px = n * HW_ + hw0 + t;
        const float* b = bb + (size_t)px * 5;
        const float cx = b[0], cy = b[1], bw = b[2], bh = b[3], th = b[4];
        const float st = sinf(th), ct = cosf(th);
        const float vx = bw * ct * 0.5f, vy = bw * st * 0.5f;
        const float wx = -bh * st * 0.5f, wy = bh * ct * 0.5f;
        const float pxs[5] = {cx, cx + vx + wx, cx - vx + wx, cx - vx - wx, cx + vx - wx};
        const float pys[5] = {cy, cy + vy + wy, cy - vy + wy, cy - vy - wy, cy + vy - wy};
        uint32* gw = geoG + (size_t)px * 32;
#pragma unroll
        for (int p = 0; p < 5; ++p) {
            float x = pxs[p] * SCALE;
            float y = pys[p] * SCALE;
            const bool valid = (y >= -1.0f) && (y <= (float)H_) &&
                               (x >= -1.0f) && (x <= (float)W_);
            y = fmaxf(y, 0.0f);
            x = fmaxf(x, 0.0f);
            int yl = min((int)y, H_ - 1);
            int xl = min((int)x, W_ - 1);
            if (yl >= H_ - 1) y = (float)yl;   // mmcv border snap: ly = 0
            if (xl >= W_ - 1) x = (float)xl;   // lx = 0
            const int yh = min(yl + 1, H_ - 1);
            const float ly = y - (float)yl, lx = x - (float)xl;
            const float hy = 1.0f - ly,     hx = 1.0f - lx;
            const int xa = min(xl, W_ - 2);
            float wA, wB;
            if (xl < W_ - 1) { wA = hx; wB = lx; }
            else             { wA = 0.0f; wB = 1.0f; }
            const float v = valid ? 1.0f : 0.0f;
            gw[p]      = (uint32)(yl * W_ + xa);
            gw[5 + p]  = (uint32)(yh * W_ + xa);
            gw[10 + p] = __float_as_uint(v * hy * wA);
            gw[15 + p] = __float_as_uint(v * hy * wB);
            gw[20 + p] = __float_as_uint(v * ly * wA);
            gw[25 + p] = __float_as_uint(v * ly * wB);
        }
        gw[30] = 0u; gw[31] = 0u;
    }

    const float* base = in + (size_t)n * C_ * HW_ + hw0 + 4 * l;
#pragma unroll
    for (int half = 0; half < 2; ++half) {
        float4 v0[4], v1[4];
#pragma unroll
        for (int r = 0; r < 4; ++r) {
            const int cp = g * 8 + half * 4 + r;
            v0[r] = *(const float4*)(base + (size_t)(2 * cp) * HW_);
            v1[r] = *(const float4*)(base + (size_t)(2 * cp + 1) * HW_);
        }
#pragma unroll
        for (int r = 0; r < 4; ++r) {
            const int cp = g * 8 + half * 4 + r;
            uint4 u;
            u.x = f2bf(v0[r].x) | (f2bf(v1[r].x) << 16);
            u.y = f2bf(v0[r].y) | (f2bf(v1[r].y) << 16);
            u.z = f2bf(v0[r].z) | (f2bf(v1[r].z) << 16);
            u.w = f2bf(v0[r].w) | (f2bf(v1[r].w) << 16);
            *(uint4*)&tile[cp * 260 + 4 * l] = u;   // b128, conflict-free
        }
    }
    __syncthreads();
    uint32* dst = outU + ((size_t)n * HW_ + hw0) * 128;
#pragma unroll 8
    for (int it = 0; it < 32; ++it) {
        const int f   = it * 1024 + t;    // f = row*128 + q
        const int row = f >> 7;
        const int q   = f & 127;
        dst[f] = tile[q * 260 + row];
    }
}

// ---------- Pass 1: refine v2 — wave per pixel, full-MLP gather ----------
// All 11 row loads (identity + 5 points x 2 rows, 1KB each covering both x
// corners across the wave halves) are issued back-to-back into registers,
// THEN the fma chain runs. launch_bounds(256,4): VGPR<=128, still 4 blocks/CU
// (LDS 33KB caps occupancy at 16 waves/CU either way).
__global__ __launch_bounds__(256, 4) void fr_refine(const uint32* __restrict__ nhwcU,
                                                    const uint32* __restrict__ geoG,
                                                    float* __restrict__ out)
{
    __shared__ float tile[32 * 260];      // [px][c], stride 260 (33 KB)
    const int t  = threadIdx.x;
    const int l  = t & 63;
    const int wv = __builtin_amdgcn_readfirstlane(t >> 6);
    const int bx = blockIdx.x;            // [0, 2048)
    // XCD x (bx&7) owns (batch, h-half); gathers are random over the batch
    // plane, so this mainly keeps each XCD's L2 on one 8MB NHWC plane.
    const int xcd = bx & 7;
    const int n   = xcd >> 1;
    const int s   = bx >> 3;              // [0, 256)
    const int h   = ((xcd & 1) << 6) | (s >> 2);
    const int w0  = (s & 3) * 32;

    const float idsel = (l < 32) ? 1.0f : 0.0f;   // identity only in A-half
    const uint32* plane = nhwcU + (size_t)n * HW_ * 128;
    const int hwb = h * W_ + w0 + wv * 8;
    const uint32* gb = geoG + ((size_t)n * HW_ + hwb) * 32;
    const int vl4 = 4 * l;

    for (int p = 0; p < 8; ++p) {
        const uint32* g = gb + p * 32;    // wave-uniform -> s_load
        const int hwp = hwb + p;

        // ---- gather offsets (scalar) ----
        int o0[5], o1[5];
#pragma unroll
        for (int q = 0; q < 5; ++q) { o0[q] = (int)g[q]; o1[q] = (int)g[5 + q]; }

        // ---- issue ALL row loads before any use (MLP = 11) ----
        const uint4 rid = *(const uint4*)(plane + (size_t)hwp * 128 + vl4);
        uint4 r0[5], r1[5];
#pragma unroll
        for (int q = 0; q < 5; ++q) {
            r0[q] = *(const uint4*)(plane + (size_t)o0[q] * 128 + vl4);
            r1[q] = *(const uint4*)(plane + (size_t)o1[q] * 128 + vl4);
        }

        float a[8];
        a[0] = idsel * blo(rid.x); a[1] = idsel * bhi(rid.x);
        a[2] = idsel * blo(rid.y); a[3] = idsel * bhi(rid.y);
        a[4] = idsel * blo(rid.z); a[5] = idsel * bhi(rid.z);
        a[6] = idsel * blo(rid.w); a[7] = idsel * bhi(rid.w);

#pragma unroll
        for (int q = 0; q < 5; ++q) {
            const float w00 = __uint_as_float(g[10 + q]);
            const float w01 = __uint_as_float(g[15 + q]);
            const float w10 = __uint_as_float(g[20 + q]);
            const float w11 = __uint_as_float(g[25 + q]);
            const float wr0 = (l < 32) ? w00 : w01;   // row0: A | B corner
            const float wr1 = (l < 32) ? w10 : w11;   // row1
            a[0] = fmaf(wr0, blo(r0[q].x), a[0]); a[1] = fmaf(wr0, bhi(r0[q].x), a[1]);
            a[2] = fmaf(wr0, blo(r0[q].y), a[2]); a[3] = fmaf(wr0, bhi(r0[q].y), a[3]);
            a[4] = fmaf(wr0, blo(r0[q].z), a[4]); a[5] = fmaf(wr0, bhi(r0[q].z), a[5]);
            a[6] = fmaf(wr0, blo(r0[q].w), a[6]); a[7] = fmaf(wr0, bhi(r0[q].w), a[7]);
            a[0] = fmaf(wr1, blo(r1[q].x), a[0]); a[1] = fmaf(wr1, bhi(r1[q].x), a[1]);
            a[2] = fmaf(wr1, blo(r1[q].y), a[2]); a[3] = fmaf(wr1, bhi(r1[q].y), a[3]);
            a[4] = fmaf(wr1, blo(r1[q].z), a[4]); a[5] = fmaf(wr1, bhi(r1[q].z), a[5]);
            a[6] = fmaf(wr1, blo(r1[q].w), a[6]); a[7] = fmaf(wr1, bhi(r1[q].w), a[7]);
        }
#pragma unroll
        for (int k = 0; k < 8; ++k) a[k] += __shfl_xor(a[k], 32, 64);
        if (l < 32) {
            const int pxl = wv * 8 + p;
            float* dst = &tile[pxl * 260 + 8 * l];
            *(float4*)dst       = make_float4(a[0], a[1], a[2], a[3]);
            *(float4*)(dst + 4) = make_float4(a[4], a[5], a[6], a[7]);
        }
    }
    __syncthreads();
    const size_t obase = (size_t)n * C_ * HW_ + h * W_ + w0;
#pragma unroll 4
    for (int it = 0; it < 32; ++it) {
        const int flat = it * 256 + t;
        const int px = flat & 31;
        const int c  = flat >> 5;
        out[obase + (size_t)c * HW_ + px] = tile[px * 260 + c];
    }
}

// ---------- Fallback (round-1 kernel) if ws too small ----------
__global__ __launch_bounds__(256) void fr_kernel(
    const float* __restrict__ feat,
    const float* __restrict__ bb,
    float* __restrict__ out)
{
    const int lane = threadIdx.x & 63;
    const int wave = threadIdx.x >> 6;
    const int tile = blockIdx.x;
    const int wt   = tile & 1;
    const int h    = (tile >> 1) & (H_ - 1);
    const int n    = tile >> 8;
    const int w    = wt * 64 + lane;
    const int cb   = blockIdx.y;

    const float* b = bb + (size_t)((n * H_ + h) * W_ + w) * 5;
    const float cx = b[0], cy = b[1], bw = b[2], bh = b[3], th = b[4];
    const float st = sinf(th), ct = cosf(th);
    const float vx = bw * ct * 0.5f, vy = bw * st * 0.5f;
    const float wx = -bh * st * 0.5f, wy = bh * ct * 0.5f;
    const float pxs[5] = {cx, cx + vx + wx, cx - vx + wx, cx - vx - wx, cx + vx - wx};
    const float pys[5] = {cy, cy + vy + wy, cy - vy + wy, cy - vy - wy, cy + vy - wy};

    int   off0[5], off1[5];
    float wgt[20];
#pragma unroll
    for (int p = 0; p < 5; ++p) {
        float x = pxs[p] * SCALE;
        float y = pys[p] * SCALE;
        const bool valid = (y >= -1.0f) && (y <= (float)H_) &&
                           (x >= -1.0f) && (x <= (float)W_);
        y = fmaxf(y, 0.0f);
        x = fmaxf(x, 0.0f);
        int yl = min((int)y, H_ - 1);
        int xl = min((int)x, W_ - 1);
        if (yl >= H_ - 1) y = (float)yl;
        if (xl >= W_ - 1) x = (float)xl;
        const int yh = min(yl + 1, H_ - 1);
        const float ly = y - (float)yl, lx = x - (float)xl;
        const float hy = 1.0f - ly,     hx = 1.0f - lx;
        const int xa = min(xl, W_ - 2);
        float wA, wB;
        if (xl < W_ - 1) { wA = hx; wB = lx; }
        else             { wA = 0.0f; wB = 1.0f; }
        const float v = valid ? 1.0f : 0.0f;
        off0[p] = yl * W_ + xa;
        off1[p] = yh * W_ + xa;
        wgt[p * 4 + 0] = v * hy * wA;
        wgt[p * 4 + 1] = v * hy * wB;
        wgt[p * 4 + 2] = v * ly * wA;
        wgt[p * 4 + 3] = v * ly * wB;
    }

    const int hw = h * W_ + w;
    const size_t planeBase = ((size_t)n * C_ + cb * 64 + wave * 16) * HW_;
    const float* fp = feat + planeBase;
    float*       op = out  + planeBase;
    for (int it = 0; it < 16; ++it) {
        float acc = fp[hw];
#pragma unroll
        for (int p = 0; p < 5; ++p) {
            acc += wgt[p * 4 + 0] * fp[off0[p]]
                 + wgt[p * 4 + 1] * fp[off0[p] + 1]
                 + wgt[p * 4 + 2] * fp[off1[p]]
                 + wgt[p * 4 + 3] * fp[off1[p] + 1];
        }
        op[hw] = acc;
        fp += HW_;
        op += HW_;
    }
}

extern "C" void kernel_launch(void* const* d_in, const int* in_sizes, int n_in,
                              void* d_out, int out_size, void* d_ws, size_t ws_size,
                              hipStream_t stream) {
    const float* feat = (const float*)d_in[0];   // [N,C,H,W] fp32
    const float* bbox = (const float*)d_in[1];   // [N,H,W,5] fp32
    float* out = (float*)d_out;

    const size_t nhwcBytes = (size_t)N_ * HW_ * C_ * 2;        // 32 MB bf16
    const size_t geoBytes  = (size_t)N_ * HW_ * 32 * 4;        // 8 MB
    if (ws_size >= nhwcBytes + geoBytes) {
        uint32* nhwcU = (uint32*)d_ws;
        uint32* geoG  = (uint32*)((char*)d_ws + nhwcBytes);
        nchw2nhwc_geo<<<dim3(HW_ / 256, N_), dim3(1024), 0, stream>>>(feat, bbox, nhwcU, geoG);
        fr_refine<<<dim3(N_ * H_ * (W_ / 32)), dim3(256), 0, stream>>>(nhwcU, geoG, out);
    } else {
        dim3 grid(N_ * H_ * (W_ / 64), C_ / 64, 1);
        fr_kernel<<<grid, dim3(256), 0, stream>>>(feat, bbox, out);
    }
}